// Round 1
// baseline (749.962 us; speedup 1.0000x reference)
//
#include <hip/hip_runtime.h>
#include <cstddef>

#define NN 1024
#define DD 6
#define TT 60
#define HH 64
#define RR 64
#define NEGV  (-10000.0f)
#define SLOPEV (0.01f)

__device__ __forceinline__ float sig_(float x)  { return 1.0f / (1.0f + __expf(-x)); }
__device__ __forceinline__ float tanh_(float x) { return 1.0f - 2.0f / (__expf(2.0f * x) + 1.0f); }

// ---------------------------------------------------------------------------
// K1: heterogeneous. Blocks [0,1024): one GRU sample per block (192 threads).
//     Blocks [1024,2048): relation-tensor reduction (sr, ssum), grid-stride.
// ---------------------------------------------------------------------------
__global__ __launch_bounds__(192, 2)
void k1_gru_rel(const float* __restrict__ x,
                const float* __restrict__ rel,
                const float* __restrict__ W,
                const float* __restrict__ fc_w,
                const float* __restrict__ Wih0, const float* __restrict__ Whh0,
                const float* __restrict__ bih0, const float* __restrict__ bhh0,
                const float* __restrict__ Wih1, const float* __restrict__ Whh1,
                const float* __restrict__ bih1, const float* __restrict__ bhh1,
                float* __restrict__ hws, float* __restrict__ sa,
                float* __restrict__ sb, float* __restrict__ hdot,
                float* __restrict__ sr, float* __restrict__ ssum)
{
    const int tid = threadIdx.x;

    if (blockIdx.x >= NN) {
        // ------------------ relation reduction ------------------
        // Each 16-lane group handles one (i,j) pair per iteration:
        // lane reads rel[p*64 + l16*4 .. +3] (float4), dot with Wv[128+..],
        // plus plain sum for the mask. Wave = 4 pairs = 1 KiB coalesced.
        const int lane = tid & 63;
        const int gw   = (blockIdx.x - NN) * 3 + (tid >> 6);   // global wave id, 0..3071
        const int sub  = lane >> 4;
        const int l16  = lane & 15;
        const float4 wv2 = *(const float4*)(W + 2 * HH + l16 * 4);
        for (int p0 = gw * 4; p0 < NN * NN; p0 += 3 * NN * 4) {
            const int p = p0 + sub;
            const float4 v = *(const float4*)(rel + (size_t)p * RR + l16 * 4);
            float dt = v.x * wv2.x + v.y * wv2.y + v.z * wv2.z + v.w * wv2.w;
            float sm = v.x + v.y + v.z + v.w;
            #pragma unroll
            for (int m = 8; m >= 1; m >>= 1) {
                dt += __shfl_xor(dt, m);
                sm += __shfl_xor(sm, m);
            }
            if (l16 == 0) { sr[p] = dt; ssum[p] = sm; }
        }
        return;
    }

    // ------------------ GRU: one sample per block ------------------
    const int n = blockIdx.x;
    const int j = tid;                       // gate row 0..191

    __shared__ __align__(16) float xl[DD * TT];   // sample's x, 360 floats
    __shared__ __align__(16) float h0s[HH];
    __shared__ __align__(16) float h1s[HH];
    __shared__ __align__(16) float A0[3 * HH];    // xg+hg (both layers reuse)
    __shared__ __align__(16) float B0[HH];        // hg of n-gate

    for (int idx = tid; idx < DD * TT; idx += 192) xl[idx] = x[n * DD * TT + idx];
    if (tid < HH) { h0s[tid] = 0.0f; h1s[tid] = 0.0f; }

    // Register-cached weight rows: thread j owns row j of Whh0/Whh1/Wih1.
    float w0[HH], w1[HH], wi1[HH], wi0[DD];
    #pragma unroll
    for (int k = 0; k < HH; k += 4) {
        const float4 a = *(const float4*)(Whh0 + j * HH + k);
        w0[k] = a.x; w0[k + 1] = a.y; w0[k + 2] = a.z; w0[k + 3] = a.w;
        const float4 bq = *(const float4*)(Whh1 + j * HH + k);
        w1[k] = bq.x; w1[k + 1] = bq.y; w1[k + 2] = bq.z; w1[k + 3] = bq.w;
        const float4 c = *(const float4*)(Wih1 + j * HH + k);
        wi1[k] = c.x; wi1[k + 1] = c.y; wi1[k + 2] = c.z; wi1[k + 3] = c.w;
    }
    #pragma unroll
    for (int d = 0; d < DD; ++d) wi0[d] = Wih0[j * DD + d];
    const float bi0 = bih0[j], bh0 = bhh0[j], bi1 = bih1[j], bh1 = bhh1[j];

    __syncthreads();

    const float4* h04 = (const float4*)h0s;
    const float4* h14 = (const float4*)h1s;

    for (int t = 0; t < TT; ++t) {
        // ---- layer 0 gates ----
        float xg = bi0;
        #pragma unroll
        for (int d = 0; d < DD; ++d) xg += wi0[d] * xl[d * TT + t];
        float hg = bh0;
        #pragma unroll
        for (int kk = 0; kk < HH / 4; ++kk) {
            const float4 hv = h04[kk];
            hg += w0[4*kk+0]*hv.x + w0[4*kk+1]*hv.y + w0[4*kk+2]*hv.z + w0[4*kk+3]*hv.w;
        }
        A0[j] = xg + hg;
        if (j >= 2 * HH) B0[j - 2 * HH] = hg;
        __syncthreads();
        if (j < HH) {
            const float r  = sig_(A0[j]);
            const float z  = sig_(A0[HH + j]);
            const float hn = B0[j];
            const float xn = A0[2 * HH + j] - hn;
            const float nn = tanh_(xn + r * hn);
            h0s[j] = (1.0f - z) * nn + z * h0s[j];
        }
        __syncthreads();
        // ---- layer 1 gates ----
        float xg1 = bi1;
        float hg1 = bh1;
        #pragma unroll
        for (int kk = 0; kk < HH / 4; ++kk) {
            const float4 a  = h04[kk];
            const float4 bq = h14[kk];
            xg1 += wi1[4*kk+0]*a.x  + wi1[4*kk+1]*a.y  + wi1[4*kk+2]*a.z  + wi1[4*kk+3]*a.w;
            hg1 += w1[4*kk+0]*bq.x  + w1[4*kk+1]*bq.y  + w1[4*kk+2]*bq.z  + w1[4*kk+3]*bq.w;
        }
        A0[j] = xg1 + hg1;
        if (j >= 2 * HH) B0[j - 2 * HH] = hg1;
        __syncthreads();
        if (j < HH) {
            const float r  = sig_(A0[j]);
            const float z  = sig_(A0[HH + j]);
            const float hn = B0[j];
            const float xn = A0[2 * HH + j] - hn;
            const float nn = tanh_(xn + r * hn);
            h1s[j] = (1.0f - z) * nn + z * h1s[j];
        }
        __syncthreads();
    }

    // ---- outputs: h, sa = h·Wv[:64], sb = h·Wv[64:128], hdot = h·fc_w[:64] ----
    if (j < HH) {
        const float hv = h1s[j];
        hws[n * HH + j] = hv;
        float pa = hv * W[j];
        float pb = hv * W[HH + j];
        float pc = hv * fc_w[j];
        #pragma unroll
        for (int off = 32; off >= 1; off >>= 1) {
            pa += __shfl_down(pa, off);
            pb += __shfl_down(pb, off);
            pc += __shfl_down(pc, off);
        }
        if (j == 0) { sa[n] = pa; sb[n] = pb; hdot[n] = pc; }
    }
}

// ---------------------------------------------------------------------------
// K2: per row i — masked leaky scores, softmax, agg = valid@h, fc head.
// ---------------------------------------------------------------------------
__global__ __launch_bounds__(256)
void k2_soft(const float* __restrict__ hws, const float* __restrict__ sa,
             const float* __restrict__ sb, const float* __restrict__ hdot,
             const float* __restrict__ sr, const float* __restrict__ ssum,
             const float* __restrict__ bscal, const float* __restrict__ fc_w,
             const float* __restrict__ fc_b, float* __restrict__ out)
{
    __shared__ float vbuf[NN];
    __shared__ float red[8];
    __shared__ float aggbuf[256];

    const int i   = blockIdx.x;
    const int tid = threadIdx.x;
    const float sai = sa[i] + bscal[0];

    float tj[4], msk[4];
    float mloc = -3.4e38f;
    #pragma unroll
    for (int q = 0; q < 4; ++q) {
        const int jj = tid + q * 256;
        float w = sai + sb[jj] + sr[(size_t)i * NN + jj];
        w = (w >= 0.0f) ? w : SLOPEV * w;
        const float m = (ssum[(size_t)i * NN + jj] != 0.0f) ? 1.0f : 0.0f;
        float tv = m * w;                     // temp = mask * weight
        tv = (tv == 0.0f) ? NEGV : tv;        // exact reference semantics
        tj[q]  = tv;
        msk[q] = m;
        mloc   = fmaxf(mloc, tv);
    }
    #pragma unroll
    for (int off = 32; off >= 1; off >>= 1) mloc = fmaxf(mloc, __shfl_xor(mloc, off));
    if ((tid & 63) == 0) red[tid >> 6] = mloc;
    __syncthreads();
    const float mx = fmaxf(fmaxf(red[0], red[1]), fmaxf(red[2], red[3]));

    float sloc = 0.0f;
    #pragma unroll
    for (int q = 0; q < 4; ++q) {
        const int jj = tid + q * 256;
        float e = __expf(tj[q] - mx);         // masked -> exp(-1e4-mx) == 0
        sloc += e;                            // denom matches reference (underflow)
        vbuf[jj] = e * msk[q];                // valid numerator (mask applied)
    }
    #pragma unroll
    for (int off = 32; off >= 1; off >>= 1) sloc += __shfl_xor(sloc, off);
    if ((tid & 63) == 0) red[4 + (tid >> 6)] = sloc;
    __syncthreads();
    const float denom = red[4] + red[5] + red[6] + red[7];
    const float inv = 1.0f / denom;

    // agg[c] = sum_j vbuf[j] * h[j,c]
    const int c = tid & 63;
    const int g = tid >> 6;
    float acc = 0.0f;
    for (int jj = g; jj < NN; jj += 4) acc += vbuf[jj] * hws[jj * HH + c];
    aggbuf[tid] = acc;
    __syncthreads();
    if (tid < 64) {
        const float aggc = (aggbuf[tid] + aggbuf[tid + 64] +
                            aggbuf[tid + 128] + aggbuf[tid + 192]) * inv;
        float p = aggc * fc_w[HH + tid];
        #pragma unroll
        for (int off = 32; off >= 1; off >>= 1) p += __shfl_down(p, off);
        if (tid == 0) out[i] = hdot[i] + p + fc_b[0];
    }
}

// ---------------------------------------------------------------------------
extern "C" void kernel_launch(void* const* d_in, const int* in_sizes, int n_in,
                              void* d_out, int out_size, void* d_ws, size_t ws_size,
                              hipStream_t stream)
{
    const float* x     = (const float*)d_in[0];
    const float* rel   = (const float*)d_in[1];
    const float* W     = (const float*)d_in[2];
    const float* b     = (const float*)d_in[3];
    const float* fc_w  = (const float*)d_in[4];
    const float* fc_b  = (const float*)d_in[5];
    const float* Wih0  = (const float*)d_in[6];
    const float* Whh0  = (const float*)d_in[7];
    const float* bih0  = (const float*)d_in[8];
    const float* bhh0  = (const float*)d_in[9];
    const float* Wih1  = (const float*)d_in[10];
    const float* Whh1  = (const float*)d_in[11];
    const float* bih1  = (const float*)d_in[12];
    const float* bhh1  = (const float*)d_in[13];

    float* ws   = (float*)d_ws;
    float* hws  = ws;                         // 1024*64
    float* sa   = hws  + NN * HH;             // 1024
    float* sb   = sa   + NN;                  // 1024
    float* hdot = sb   + NN;                  // 1024
    float* sr   = hdot + NN;                  // 1024*1024
    float* ssum = sr   + NN * NN;             // 1024*1024

    k1_gru_rel<<<2 * NN, 192, 0, stream>>>(x, rel, W, fc_w,
                                           Wih0, Whh0, bih0, bhh0,
                                           Wih1, Whh1, bih1, bhh1,
                                           hws, sa, sb, hdot, sr, ssum);
    k2_soft<<<NN, 256, 0, stream>>>(hws, sa, sb, hdot, sr, ssum,
                                    b, fc_w, fc_b, (float*)d_out);
}